// Round 1
// baseline (1254.018 us; speedup 1.0000x reference)
//
#include <hip/hip_runtime.h>
#include <math.h>

#define S_TOTAL 4096
#define DDIM    512
#define AXES    72
#define NPROJ   864            // AXES * PARAMS
#define T_PROP  600
#define SA      (S_TOTAL*AXES) // 294912
#define LN_EPS  1e-5f

__device__ __forceinline__ float softplus_f(float x) {
    // log1p(exp(x)) stable form
    return fmaxf(x, 0.f) + log1pf(expf(-fabsf(x)));
}

// ---------------- 1. LayerNorm row stats (mean, rstd) ----------------
__global__ __launch_bounds__(256) void ln_stats_kernel(const float* __restrict__ x,
                                                       float* __restrict__ mu,
                                                       float* __restrict__ rstd) {
    int wave = threadIdx.x >> 6;
    int lane = threadIdx.x & 63;
    int row  = blockIdx.x * 4 + wave;             // 1024 blocks * 4 waves = 4096 rows
    const float4* xr = reinterpret_cast<const float4*>(x + (size_t)row * DDIM);
    float sum = 0.f, ssq = 0.f;
#pragma unroll
    for (int c = 0; c < 2; ++c) {
        float4 v = xr[lane + 64*c];
        sum += (v.x + v.y) + (v.z + v.w);
        ssq += v.x*v.x + v.y*v.y + v.z*v.z + v.w*v.w;
    }
#pragma unroll
    for (int off = 32; off > 0; off >>= 1) {
        sum += __shfl_down(sum, off);
        ssq += __shfl_down(ssq, off);
    }
    if (lane == 0) {
        float mean = sum * (1.f/DDIM);
        float var  = ssq * (1.f/DDIM) - mean*mean;
        mu[row]   = mean;
        rstd[row] = rsqrtf(var + LN_EPS);
    }
}

// ---------------- 2. fused LN + GEMM + param transform ----------------
// C[s][n] = xn[s][:] . W[:][n] + b[n], xn computed on the fly from stats.
// BM=64, BN=64, BK=16, 256 threads, 4x4 per-thread tile.
#define BM 64
#define BN 64
#define BK 16

__global__ __launch_bounds__(256) void ln_gemm_kernel(
        const float* __restrict__ x, const float* __restrict__ gamma,
        const float* __restrict__ beta, const float* __restrict__ W,
        const float* __restrict__ bias, const float* __restrict__ mu,
        const float* __restrict__ rstd,
        float* __restrict__ P, float* __restrict__ out) {
    __shared__ float As[BK][BM + 4];   // stride 68 words: 16B-aligned frags, 2-way max on stores
    __shared__ float Bs[BK][BN];
    __shared__ float mu_s[BM], rs_s[BM];

    int tid   = threadIdx.x;
    int sBase = blockIdx.x * BM;
    int nBase = blockIdx.y * BN;
    if (tid < BM) { mu_s[tid] = mu[sBase + tid]; rs_s[tid] = rstd[sBase + tid]; }

    int tm = (tid >> 4) * 4;      // 0..60
    int tn = (tid & 15) * 4;      // 0..60
    int arow = tid >> 2;          // 0..63
    int acol = (tid & 3) * 4;     // 0,4,8,12
    int brow = tid >> 4;          // 0..15
    int bcol = (tid & 15) * 4;    // 0..60

    float acc[4][4] = {};
    __syncthreads();

    for (int k0 = 0; k0 < DDIM; k0 += BK) {
        // stage A (with fused layernorm), transposed to [k][m]
        {
            float4 xv = *reinterpret_cast<const float4*>(&x[(size_t)(sBase + arow)*DDIM + k0 + acol]);
            float4 gv = *reinterpret_cast<const float4*>(&gamma[k0 + acol]);
            float4 bv = *reinterpret_cast<const float4*>(&beta[k0 + acol]);
            float m = mu_s[arow], r = rs_s[arow];
            As[acol+0][arow] = (xv.x - m)*r*gv.x + bv.x;
            As[acol+1][arow] = (xv.y - m)*r*gv.y + bv.y;
            As[acol+2][arow] = (xv.z - m)*r*gv.z + bv.z;
            As[acol+3][arow] = (xv.w - m)*r*gv.w + bv.w;
        }
        // stage B
        {
            int n = nBase + bcol;
            float4 wv = make_float4(0.f, 0.f, 0.f, 0.f);
            if (n < NPROJ)
                wv = *reinterpret_cast<const float4*>(&W[(size_t)(k0 + brow)*NPROJ + n]);
            *reinterpret_cast<float4*>(&Bs[brow][bcol]) = wv;
        }
        __syncthreads();
#pragma unroll
        for (int kk = 0; kk < BK; ++kk) {
            float4 a4 = *reinterpret_cast<const float4*>(&As[kk][tm]);
            float4 b4 = *reinterpret_cast<const float4*>(&Bs[kk][tn]);
            float af[4] = {a4.x, a4.y, a4.z, a4.w};
            float bf[4] = {b4.x, b4.y, b4.z, b4.w};
#pragma unroll
            for (int i = 0; i < 4; ++i)
#pragma unroll
                for (int j = 0; j < 4; ++j)
                    acc[i][j] = fmaf(af[i], bf[j], acc[i][j]);
        }
        __syncthreads();
    }

    // epilogue: bias + per-param transform
#pragma unroll
    for (int mi = 0; mi < 4; ++mi) {
        int s = sBase + tm + mi;
#pragma unroll
        for (int ni = 0; ni < 4; ++ni) {
            int n = nBase + tn + ni;
            if (n >= NPROJ) continue;
            float val = acc[mi][ni] + bias[n];
            int ip = n / AXES;           // param index 0..11
            int a  = n - ip * AXES;      // axis
            size_t sa = (size_t)s * AXES + a;
            switch (ip) {
                case 0:  P[0*(size_t)SA + sa] = sqrtf(softplus_f(val));        break; // omega
                case 1:  P[1*(size_t)SA + sa] = expf(-0.5f*softplus_f(val));   break; // decay/step
                case 2:  P[2*(size_t)SA + sa] = sqrtf(softplus_f(val));        break; // omega_th
                case 3:  P[3*(size_t)SA + sa] = expf(-0.5f*softplus_f(val));   break; // decay_th
                case 4:  P[4*(size_t)SA + sa] = val;                           break; // c
                case 5:  P[5*(size_t)SA + sa] = val;                           break; // c_th
                case 6:  P[6*(size_t)SA + sa] = val;                           break; // phi
                case 7:  P[7*(size_t)SA + sa] = val;                           break; // phi_th
                case 8:  out[1*(size_t)SA + (size_t)a*S_TOTAL + s] = val;                 break; // acc_base
                case 9:  out[2*(size_t)SA + (size_t)a*S_TOTAL + s] = softplus_f(val);     break; // acc_std
                case 10: out[3*(size_t)SA + (size_t)a*S_TOTAL + s] = val;                 break; // gyro_base
                case 11: out[4*(size_t)SA + (size_t)a*S_TOTAL + s] = softplus_f(val);     break; // gyro_std
            }
        }
    }
}

// ---------------- 3. oscillator recurrence + diagonal scatter ----------------
// thread owns (s, a); w_{t+1} = w_t * r, vals = Im(w); LDS accumulate, then
// global atomic flush into kinematics.
#define TS 64
#define AA 8
#define JROWS (TS + T_PROP)    // 664

__global__ __launch_bounds__(512) void osc_kernel(const float* __restrict__ P,
                                                  float* __restrict__ kin) {
    __shared__ float accs[JROWS * AA];   // 21248 B
    int tid = threadIdx.x;
    for (int i = tid; i < JROWS*AA; i += 512) accs[i] = 0.f;
    __syncthreads();

    int sBase = blockIdx.x * TS;
    int aBase = blockIdx.y * AA;
    int al = tid & (AA-1);
    int sl = tid >> 3;               // 0..63
    size_t sa = (size_t)(sBase + sl) * AXES + aBase + al;

    float om1 = P[0*(size_t)SA + sa], dc1 = P[1*(size_t)SA + sa];
    float om2 = P[2*(size_t)SA + sa], dc2 = P[3*(size_t)SA + sa];
    float c1  = P[4*(size_t)SA + sa], c2  = P[5*(size_t)SA + sa];
    float ph1 = P[6*(size_t)SA + sa], ph2 = P[7*(size_t)SA + sa];

    float sv, cv;
    sincosf(ph1, &sv, &cv);
    float w1r = c1*cv, w1i = c1*sv;
    sincosf(om1, &sv, &cv);
    float r1r = dc1*cv, r1i = dc1*sv;
    sincosf(ph2, &sv, &cv);
    float w2r = c2*cv, w2i = c2*sv;
    sincosf(om2, &sv, &cv);
    float r2r = dc2*cv, r2i = dc2*sv;

    float* ap = &accs[sl*AA + al];
#pragma unroll 4
    for (int t = 0; t < T_PROP; ++t) {
        atomicAdd(ap, w1i + w2i);        // ds_add_f32
        ap += AA;
        float n1r = w1r*r1r - w1i*r1i;
        float n1i = fmaf(w1r, r1i, w1i*r1r);
        w1r = n1r; w1i = n1i;
        float n2r = w2r*r2r - w2i*r2i;
        float n2i = fmaf(w2r, r2i, w2i*r2r);
        w2r = n2r; w2i = n2i;
    }
    __syncthreads();

    // flush, a-major so consecutive threads hit consecutive global words
    for (int i = tid; i < JROWS*AA; i += 512) {
        int a2 = i / JROWS;
        int r  = i - a2*JROWS;
        int j  = sBase + r;
        if (j < S_TOTAL) {
            unsafeAtomicAdd(&kin[(size_t)(aBase + a2)*S_TOTAL + j], accs[r*AA + a2]);
        }
    }
}

// ---------------- launch ----------------
extern "C" void kernel_launch(void* const* d_in, const int* in_sizes, int n_in,
                              void* d_out, int out_size, void* d_ws, size_t ws_size,
                              hipStream_t stream) {
    const float* x     = (const float*)d_in[0];
    const float* gamma = (const float*)d_in[1];
    const float* beta  = (const float*)d_in[2];
    const float* W     = (const float*)d_in[3];
    const float* b     = (const float*)d_in[4];
    float* out = (float*)d_out;

    float* P    = (float*)d_ws;           // 8 * SA floats = 9.44 MB
    float* mu   = P + 8*(size_t)SA;       // 4096
    float* rstd = mu + S_TOTAL;           // 4096

    // zero only the kinematics region (outputs 1..4 are fully overwritten)
    hipMemsetAsync(d_out, 0, (size_t)SA * sizeof(float), stream);

    ln_stats_kernel<<<dim3(S_TOTAL/4), dim3(256), 0, stream>>>(x, mu, rstd);

    dim3 gB(S_TOTAL/BM, (NPROJ + BN - 1)/BN);   // 64 x 14
    ln_gemm_kernel<<<gB, dim3(256), 0, stream>>>(x, gamma, beta, W, b, mu, rstd, P, out);

    osc_kernel<<<dim3(S_TOTAL/TS, AXES/AA), dim3(512), 0, stream>>>(P, out);
}

// Round 2
// 151.433 us; speedup vs baseline: 8.2810x; 8.2810x over previous
//
#include <hip/hip_runtime.h>
#include <math.h>

#define S_TOTAL 4096
#define DDIM    512
#define AXES    72
#define NPROJ   864            // AXES * PARAMS
#define T_PROP  600
#define SA      (S_TOTAL*AXES) // 294912
#define LN_EPS  1e-5f

__device__ __forceinline__ float softplus_f(float x) {
    return fmaxf(x, 0.f) + log1pf(expf(-fabsf(x)));
}

// ---------------- 1. LayerNorm row stats (mean, rstd) ----------------
__global__ __launch_bounds__(256) void ln_stats_kernel(const float* __restrict__ x,
                                                       float* __restrict__ mu,
                                                       float* __restrict__ rstd) {
    int wave = threadIdx.x >> 6;
    int lane = threadIdx.x & 63;
    int row  = blockIdx.x * 4 + wave;
    const float4* xr = reinterpret_cast<const float4*>(x + (size_t)row * DDIM);
    float sum = 0.f, ssq = 0.f;
#pragma unroll
    for (int c = 0; c < 2; ++c) {
        float4 v = xr[lane + 64*c];
        sum += (v.x + v.y) + (v.z + v.w);
        ssq += v.x*v.x + v.y*v.y + v.z*v.z + v.w*v.w;
    }
#pragma unroll
    for (int off = 32; off > 0; off >>= 1) {
        sum += __shfl_down(sum, off);
        ssq += __shfl_down(ssq, off);
    }
    if (lane == 0) {
        float mean = sum * (1.f/DDIM);
        float var  = ssq * (1.f/DDIM) - mean*mean;
        mu[row]   = mean;
        rstd[row] = rsqrtf(var + LN_EPS);
    }
}

// ---------------- 2. fused LN + GEMM + param transform ----------------
// P layout: [param][axis][s]  (each param plane SA floats, axis-major rows of S)
#define BM 64
#define BN 64
#define BK 16

__global__ __launch_bounds__(256) void ln_gemm_kernel(
        const float* __restrict__ x, const float* __restrict__ gamma,
        const float* __restrict__ beta, const float* __restrict__ W,
        const float* __restrict__ bias, const float* __restrict__ mu,
        const float* __restrict__ rstd,
        float* __restrict__ P, float* __restrict__ out) {
    __shared__ float As[BK][BM + 4];
    __shared__ float Bs[BK][BN];
    __shared__ float mu_s[BM], rs_s[BM];

    int tid   = threadIdx.x;
    int sBase = blockIdx.x * BM;
    int nBase = blockIdx.y * BN;
    if (tid < BM) { mu_s[tid] = mu[sBase + tid]; rs_s[tid] = rstd[sBase + tid]; }

    int tm = (tid >> 4) * 4;      // s-offset 0..60
    int tn = (tid & 15) * 4;      // n-offset 0..60
    int arow = tid >> 2;
    int acol = (tid & 3) * 4;
    int brow = tid >> 4;
    int bcol = (tid & 15) * 4;

    float acc[4][4] = {};
    __syncthreads();

    for (int k0 = 0; k0 < DDIM; k0 += BK) {
        {
            float4 xv = *reinterpret_cast<const float4*>(&x[(size_t)(sBase + arow)*DDIM + k0 + acol]);
            float4 gv = *reinterpret_cast<const float4*>(&gamma[k0 + acol]);
            float4 bv = *reinterpret_cast<const float4*>(&beta[k0 + acol]);
            float m = mu_s[arow], r = rs_s[arow];
            As[acol+0][arow] = (xv.x - m)*r*gv.x + bv.x;
            As[acol+1][arow] = (xv.y - m)*r*gv.y + bv.y;
            As[acol+2][arow] = (xv.z - m)*r*gv.z + bv.z;
            As[acol+3][arow] = (xv.w - m)*r*gv.w + bv.w;
        }
        {
            int n = nBase + bcol;
            float4 wv = make_float4(0.f, 0.f, 0.f, 0.f);
            if (n < NPROJ)
                wv = *reinterpret_cast<const float4*>(&W[(size_t)(k0 + brow)*NPROJ + n]);
            *reinterpret_cast<float4*>(&Bs[brow][bcol]) = wv;
        }
        __syncthreads();
#pragma unroll
        for (int kk = 0; kk < BK; ++kk) {
            float4 a4 = *reinterpret_cast<const float4*>(&As[kk][tm]);
            float4 b4 = *reinterpret_cast<const float4*>(&Bs[kk][tn]);
            float af[4] = {a4.x, a4.y, a4.z, a4.w};
            float bf[4] = {b4.x, b4.y, b4.z, b4.w};
#pragma unroll
            for (int i = 0; i < 4; ++i)
#pragma unroll
                for (int j = 0; j < 4; ++j)
                    acc[i][j] = fmaf(af[i], bf[j], acc[i][j]);
        }
        __syncthreads();
    }

    // epilogue: bias + transform; 4 consecutive s per float4 store
    int s0 = sBase + tm;
#pragma unroll
    for (int ni = 0; ni < 4; ++ni) {
        int n = nBase + tn + ni;
        if (n >= NPROJ) continue;
        float bv = bias[n];
        int ip = n / AXES;
        int a  = n - ip * AXES;
        float v[4];
#pragma unroll
        for (int mi = 0; mi < 4; ++mi) v[mi] = acc[mi][ni] + bv;

        float4 r4;
        float* dst;
        switch (ip) {
            case 0: case 2: { // omega = sqrt(softplus)
#pragma unroll
                for (int mi = 0; mi < 4; ++mi) v[mi] = sqrtf(softplus_f(v[mi]));
                dst = &P[(size_t)ip/2*2*(size_t)SA + ((size_t)(ip==0?0:2))*0]; // placeholder, set below
                dst = &P[(size_t)(ip)*(size_t)SA + (size_t)a*S_TOTAL + s0];
                break;
            }
            case 1: case 3: { // decay factor e^{-sp/2}
#pragma unroll
                for (int mi = 0; mi < 4; ++mi) v[mi] = expf(-0.5f*softplus_f(v[mi]));
                dst = &P[(size_t)(ip)*(size_t)SA + (size_t)a*S_TOTAL + s0];
                break;
            }
            case 4: case 5: case 6: case 7: { // c, c_th, phi, phi_th raw
                dst = &P[(size_t)(ip)*(size_t)SA + (size_t)a*S_TOTAL + s0];
                break;
            }
            case 8: { // acc_base
                dst = &out[1*(size_t)SA + (size_t)a*S_TOTAL + s0];
                break;
            }
            case 9: { // acc_std
#pragma unroll
                for (int mi = 0; mi < 4; ++mi) v[mi] = softplus_f(v[mi]);
                dst = &out[2*(size_t)SA + (size_t)a*S_TOTAL + s0];
                break;
            }
            case 10: { // gyro_base
                dst = &out[3*(size_t)SA + (size_t)a*S_TOTAL + s0];
                break;
            }
            default: { // 11: gyro_std
#pragma unroll
                for (int mi = 0; mi < 4; ++mi) v[mi] = softplus_f(v[mi]);
                dst = &out[4*(size_t)SA + (size_t)a*S_TOTAL + s0];
                break;
            }
        }
        r4.x = v[0]; r4.y = v[1]; r4.z = v[2]; r4.w = v[3];
        *reinterpret_cast<float4*>(dst) = r4;
    }
}

// ---------------- 3. oscillator recurrence, register-rotation scatter ----------------
// wave owns 64 consecutive s for one axis. Contribution of lane l at step
// dt (within a 64-step chunk) belongs to output jBase + ((l+dt) mod 64)
// (+64 on wrap). ds_bpermute rotates values so lane m accumulates its own
// two outputs in registers; one global_atomic_add_f32 flush per chunk.
__global__ __launch_bounds__(256) void osc_kernel(const float* __restrict__ P,
                                                  float* __restrict__ kin) {
    int lane  = threadIdx.x & 63;
    int wv    = threadIdx.x >> 6;           // 0..3
    int sBase = blockIdx.x * 64;
    int a     = blockIdx.y * 4 + wv;        // 0..71
    size_t base = (size_t)a * S_TOTAL + sBase + lane;

    float om1 = P[0*(size_t)SA + base], dc1 = P[1*(size_t)SA + base];
    float om2 = P[2*(size_t)SA + base], dc2 = P[3*(size_t)SA + base];
    float c1  = P[4*(size_t)SA + base], c2  = P[5*(size_t)SA + base];
    float ph1 = P[6*(size_t)SA + base], ph2 = P[7*(size_t)SA + base];

    float sv, cv;
    sincosf(ph1, &sv, &cv);
    float w1r = c1*cv, w1i = c1*sv;
    sincosf(om1, &sv, &cv);
    float r1r = dc1*cv, r1i = dc1*sv;
    sincosf(ph2, &sv, &cv);
    float w2r = c2*cv, w2i = c2*sv;
    sincosf(om2, &sv, &cv);
    float r2r = dc2*cv, r2i = dc2*sv;

    float acc0 = 0.f, acc1 = 0.f;
    int bytes = lane << 2;                  // bpermute src byte addr, = ((lane-dt)&63)*4
    float* kinA = kin + (size_t)a * S_TOTAL;
    int jBase = sBase;

#pragma unroll 1
    for (int c = 0; c < 10; ++c) {
        int steps = (c == 9) ? (T_PROP - 9*64) : 64;   // 24 on the last chunk
#pragma unroll 8
        for (int dt = 0; dt < steps; ++dt) {
            float v = w1i + w2i;
            int vri = __builtin_amdgcn_ds_bpermute(bytes, __float_as_int(v));
            bytes = (bytes - 4) & 255;
            float vr = __int_as_float(vri);
            float sel = (lane >= dt) ? vr : 0.f;
            acc0 += sel;
            acc1 += vr - sel;
            float n1r = fmaf(w1r, r1r, -(w1i*r1i));
            float n1i = fmaf(w1r, r1i,   w1i*r1r);
            w1r = n1r; w1i = n1i;
            float n2r = fmaf(w2r, r2r, -(w2i*r2i));
            float n2i = fmaf(w2r, r2i,   w2i*r2r);
            w2r = n2r; w2i = n2i;
        }
        int j = jBase + lane;
        if (j < S_TOTAL) unsafeAtomicAdd(&kinA[j], acc0);
        acc0 = acc1; acc1 = 0.f;
        jBase += 64;
        bytes = lane << 2;
    }
    int j = jBase + lane;
    if (j < S_TOTAL) unsafeAtomicAdd(&kinA[j], acc0);
}

// ---------------- launch ----------------
extern "C" void kernel_launch(void* const* d_in, const int* in_sizes, int n_in,
                              void* d_out, int out_size, void* d_ws, size_t ws_size,
                              hipStream_t stream) {
    const float* x     = (const float*)d_in[0];
    const float* gamma = (const float*)d_in[1];
    const float* beta  = (const float*)d_in[2];
    const float* W     = (const float*)d_in[3];
    const float* b     = (const float*)d_in[4];
    float* out = (float*)d_out;

    float* P    = (float*)d_ws;           // 8 * SA floats = 9.44 MB
    float* mu   = P + 8*(size_t)SA;
    float* rstd = mu + S_TOTAL;

    hipMemsetAsync(d_out, 0, (size_t)SA * sizeof(float), stream);

    ln_stats_kernel<<<dim3(S_TOTAL/4), dim3(256), 0, stream>>>(x, mu, rstd);

    dim3 gB(S_TOTAL/BM, (NPROJ + BN - 1)/BN);
    ln_gemm_kernel<<<gB, dim3(256), 0, stream>>>(x, gamma, beta, W, b, mu, rstd, P, out);

    osc_kernel<<<dim3(S_TOTAL/64, AXES/4), dim3(256), 0, stream>>>(P, out);
}

// Round 3
// 113.926 us; speedup vs baseline: 11.0073x; 1.3292x over previous
//
#include <hip/hip_runtime.h>
#include <math.h>

#define S_TOTAL 4096
#define DDIM    512
#define AXES    72
#define NPROJ   864
#define T_PROP  600
#define SA      (S_TOTAL*AXES)
#define LN_EPS  1e-5f

typedef __attribute__((ext_vector_type(8))) short short8;
typedef __attribute__((ext_vector_type(4))) float f32x4;

__device__ __forceinline__ float softplus_f(float x) {
    return fmaxf(x, 0.f) + log1pf(expf(-fabsf(x)));
}
__device__ __forceinline__ unsigned short bf_hi(float f) {
    return (unsigned short)(__float_as_uint(f) >> 16);
}

// ---------------- 1. LayerNorm row stats ----------------
__global__ __launch_bounds__(256) void ln_stats_kernel(const float* __restrict__ x,
                                                       float* __restrict__ mu,
                                                       float* __restrict__ rstd) {
    int wave = threadIdx.x >> 6;
    int lane = threadIdx.x & 63;
    int row  = blockIdx.x * 4 + wave;
    const float4* xr = reinterpret_cast<const float4*>(x + (size_t)row * DDIM);
    float sum = 0.f, ssq = 0.f;
#pragma unroll
    for (int c = 0; c < 2; ++c) {
        float4 v = xr[lane + 64*c];
        sum += (v.x + v.y) + (v.z + v.w);
        ssq += v.x*v.x + v.y*v.y + v.z*v.z + v.w*v.w;
    }
#pragma unroll
    for (int off = 32; off > 0; off >>= 1) {
        sum += __shfl_down(sum, off);
        ssq += __shfl_down(ssq, off);
    }
    if (lane == 0) {
        float mean = sum * (1.f/DDIM);
        float var  = ssq * (1.f/DDIM) - mean*mean;
        mu[row]   = mean;
        rstd[row] = rsqrtf(var + LN_EPS);
    }
}

// ---------------- 2. prep: xn bf16 split + W^T bf16 split ----------------
__global__ __launch_bounds__(256) void prep_kernel(
        const float* __restrict__ x, const float* __restrict__ gamma,
        const float* __restrict__ beta, const float* __restrict__ W,
        const float* __restrict__ mu, const float* __restrict__ rstd,
        unsigned short* __restrict__ Ahi, unsigned short* __restrict__ Alo,
        unsigned short* __restrict__ WhiT, unsigned short* __restrict__ WloT) {
    __shared__ float Wt[32][33];
    int tid = threadIdx.x;
    int b = blockIdx.x;
    if (b < 2048) {
        // xn split: 4 elems/thread
        int i4 = (b*256 + tid) * 4;
        int row = i4 >> 9, col = i4 & 511;
        float m = mu[row], r = rstd[row];
        float4 xv = *reinterpret_cast<const float4*>(&x[i4]);
        float4 gv = *reinterpret_cast<const float4*>(&gamma[col]);
        float4 bv = *reinterpret_cast<const float4*>(&beta[col]);
        float xn[4] = {(xv.x-m)*r*gv.x+bv.x, (xv.y-m)*r*gv.y+bv.y,
                       (xv.z-m)*r*gv.z+bv.z, (xv.w-m)*r*gv.w+bv.w};
        ushort4 h4, l4;
        unsigned short* hp = &h4.x;
        unsigned short* lp = &l4.x;
#pragma unroll
        for (int j = 0; j < 4; ++j) {
            unsigned short hi = bf_hi(xn[j]);
            float fhi = __uint_as_float((unsigned)hi << 16);
            hp[j] = hi;
            lp[j] = bf_hi(xn[j] - fhi);
        }
        *reinterpret_cast<ushort4*>(&Ahi[i4]) = h4;
        *reinterpret_cast<ushort4*>(&Alo[i4]) = l4;
    } else {
        // W transpose + split: 32x32 tiles, 27 n-tiles x 16 k-tiles
        int wb = b - 2048;
        int bk = wb / 27, bn = wb - bk*27;
        int tx = tid & 31, ty0 = tid >> 5;
#pragma unroll
        for (int rr = 0; rr < 4; ++rr) {
            int ty = ty0 + rr*8;
            Wt[ty][tx] = W[(size_t)(bk*32 + ty)*NPROJ + bn*32 + tx];
        }
        __syncthreads();
#pragma unroll
        for (int rr = 0; rr < 4; ++rr) {
            int ny = ty0 + rr*8;
            int n = bn*32 + ny;
            int k = bk*32 + tx;
            float f = Wt[tx][ny];
            unsigned short hi = bf_hi(f);
            float fhi = __uint_as_float((unsigned)hi << 16);
            WhiT[(size_t)n*DDIM + k] = hi;
            WloT[(size_t)n*DDIM + k] = bf_hi(f - fhi);
        }
    }
}

// ---------------- 3. split-bf16 MFMA GEMM + param transforms ----------------
// C^T trick: D = W^T-frag (A-op) x xn-frag (B-op) so D cols = s (coalesced).
// Virtual K=1536: seg0 Ahi*WhiT, seg1 Alo*WhiT, seg2 Ahi*WloT.
#define GBM 64
#define GBN 96
#define GBK 64

__global__ __launch_bounds__(256) void gemm_kernel(
        const unsigned short* __restrict__ Ahi, const unsigned short* __restrict__ Alo,
        const unsigned short* __restrict__ WhiT, const unsigned short* __restrict__ WloT,
        const float* __restrict__ bias,
        float* __restrict__ P, float* __restrict__ out) {
    __shared__ __align__(16) unsigned short Xs[64][72];   // [s][k + 8 pad]
    __shared__ __align__(16) unsigned short Ws2[96][72];  // [n][k + 8 pad]

    int tid  = threadIdx.x;
    int lane = tid & 63;
    int wv   = tid >> 6;
    int wm   = wv & 1;       // s-half (32 rows)
    int wn   = wv >> 1;      // n-half (48 cols)
    int sBase = blockIdx.x * GBM;
    int nBase = blockIdx.y * GBN;

    f32x4 acc[2][3] = {};
    uint4 pfX[2], pfW[3];

    int rowX[2], c16X[2], rowW[3], c16W[3];
#pragma unroll
    for (int j = 0; j < 2; ++j) { int ch = j*256 + tid; rowX[j] = ch >> 3; c16X[j] = ch & 7; }
#pragma unroll
    for (int j = 0; j < 3; ++j) { int ch = j*256 + tid; rowW[j] = ch >> 3; c16W[j] = ch & 7; }

#pragma unroll 1
    for (int kt = 0; kt < 24; ++kt) {
        // issue loads for this tile (kt==0) happened below via rotation: load now
        {
            int seg = kt >> 3;
            int k0  = (kt & 7) * GBK;
            const unsigned short* xs = (seg == 1) ? Alo : Ahi;
            const unsigned short* ws = (seg == 2) ? WloT : WhiT;
#pragma unroll
            for (int j = 0; j < 2; ++j)
                pfX[j] = *reinterpret_cast<const uint4*>(xs + (size_t)(sBase+rowX[j])*DDIM + k0 + c16X[j]*8);
#pragma unroll
            for (int j = 0; j < 3; ++j)
                pfW[j] = *reinterpret_cast<const uint4*>(ws + (size_t)(nBase+rowW[j])*DDIM + k0 + c16W[j]*8);
        }
#pragma unroll
        for (int j = 0; j < 2; ++j)
            *reinterpret_cast<uint4*>(&Xs[rowX[j]][c16X[j]*8]) = pfX[j];
#pragma unroll
        for (int j = 0; j < 3; ++j)
            *reinterpret_cast<uint4*>(&Ws2[rowW[j]][c16W[j]*8]) = pfW[j];
        __syncthreads();

#pragma unroll
        for (int kk = 0; kk < 2; ++kk) {
            int koff = kk*32 + ((lane>>4)<<3);
            short8 xf[2], wf[3];
#pragma unroll
            for (int mi = 0; mi < 2; ++mi)
                xf[mi] = *reinterpret_cast<const short8*>(&Xs[wm*32 + mi*16 + (lane&15)][koff]);
#pragma unroll
            for (int nf = 0; nf < 3; ++nf)
                wf[nf] = *reinterpret_cast<const short8*>(&Ws2[wn*48 + nf*16 + (lane&15)][koff]);
#pragma unroll
            for (int mi = 0; mi < 2; ++mi)
#pragma unroll
                for (int nf = 0; nf < 3; ++nf)
                    acc[mi][nf] = __builtin_amdgcn_mfma_f32_16x16x32_bf16(wf[nf], xf[mi], acc[mi][nf], 0, 0, 0);
        }
        __syncthreads();
    }

    // epilogue: D rows = n (param dim), D cols = s (coalesced stores)
    int sCol = sBase + wm*32 + (lane & 15);
    int nRowBase = nBase + wn*48 + ((lane>>4)<<2);
#pragma unroll
    for (int mi = 0; mi < 2; ++mi) {
        int s = sCol + mi*16;
#pragma unroll
        for (int nf = 0; nf < 3; ++nf) {
#pragma unroll
            for (int r = 0; r < 4; ++r) {
                int n = nRowBase + nf*16 + r;
                float val = acc[mi][nf][r] + bias[n];
                float sp  = softplus_f(val);
                float sq  = sqrtf(sp);
                int ip = (n * 3641) >> 18;   // n / 72, exact for n < 864
                int a  = n - ip * 72;
                float res = val;
                if (ip == 0 || ip == 2) res = sq;                          // omega = sqrt(sp)
                else if (ip == 1 || ip == 3 || ip == 9 || ip == 11) res = sp; // d / stds
                float* dst = (ip < 8) ? (P + (size_t)ip * SA)
                                      : (out + (size_t)(ip - 7) * SA);
                dst[(size_t)a * S_TOTAL + s] = res;
            }
        }
    }
}

// ---------------- 4. oscillator recurrence, register-rotation scatter ----------------
// wave owns 64 consecutive s for one axis + one t-half (t0 in {0,300}).
__global__ __launch_bounds__(256) void osc_kernel(const float* __restrict__ P,
                                                  float* __restrict__ kin) {
    int tid  = threadIdx.x;
    int lane = tid & 63;
    int wv   = tid >> 6;
    int sBase = blockIdx.x * 64;
    int a  = blockIdx.y * 2 + (wv >> 1);
    int t0 = (wv & 1) * 300;
    if (sBase + t0 >= S_TOTAL) return;   // nothing lands below S_TOTAL

    size_t base = (size_t)a * S_TOTAL + sBase + lane;
    float om1 = P[0*(size_t)SA + base], d1 = P[1*(size_t)SA + base];
    float om2 = P[2*(size_t)SA + base], d2 = P[3*(size_t)SA + base];
    float c1  = P[4*(size_t)SA + base], c2  = P[5*(size_t)SA + base];
    float ph1 = P[6*(size_t)SA + base], ph2 = P[7*(size_t)SA + base];

    float t0f = (float)t0;
    float sv, cv;
    float amp1 = c1 * expf(-0.5f * d1 * t0f);
    sincosf(fmaf(t0f, om1, ph1), &sv, &cv);
    float w1r = amp1 * cv, w1i = amp1 * sv;
    float dcf1 = expf(-0.5f * d1);
    sincosf(om1, &sv, &cv);
    float r1r = dcf1 * cv, r1i = dcf1 * sv;
    float amp2 = c2 * expf(-0.5f * d2 * t0f);
    sincosf(fmaf(t0f, om2, ph2), &sv, &cv);
    float w2r = amp2 * cv, w2i = amp2 * sv;
    float dcf2 = expf(-0.5f * d2);
    sincosf(om2, &sv, &cv);
    float r2r = dcf2 * cv, r2i = dcf2 * sv;

    float acc0 = 0.f, acc1 = 0.f;
    int bytes = lane << 2;
    float* kinA = kin + (size_t)a * S_TOTAL;
    int jBase = sBase + t0;
    bool alive = true;

#pragma unroll 1
    for (int c = 0; c < 5; ++c) {
        int steps = (c < 4) ? 64 : 44;   // 4*64 + 44 = 300
#pragma unroll 4
        for (int dt = 0; dt < steps; ++dt) {
            float v = w1i + w2i;
            int vri = __builtin_amdgcn_ds_bpermute(bytes, __float_as_int(v));
            bytes = (bytes - 4) & 255;
            float vr = __int_as_float(vri);
            float sel = (lane >= dt) ? vr : 0.f;
            acc0 += sel;
            acc1 += vr - sel;
            float n1r = fmaf(w1r, r1r, -(w1i*r1i));
            float n1i = fmaf(w1r, r1i,   w1i*r1r);
            w1r = n1r; w1i = n1i;
            float n2r = fmaf(w2r, r2r, -(w2i*r2i));
            float n2i = fmaf(w2r, r2i,   w2i*r2r);
            w2r = n2r; w2i = n2i;
        }
        int j = jBase + lane;
        if (j < S_TOTAL) unsafeAtomicAdd(&kinA[j], acc0);
        acc0 = acc1; acc1 = 0.f;
        jBase += 64;
        bytes = lane << 2;
        if (jBase >= S_TOTAL) { alive = false; break; }
    }
    if (alive) {
        int j = jBase + lane;
        if (j < S_TOTAL) unsafeAtomicAdd(&kinA[j], acc0);
    }
}

// ---------------- launch ----------------
extern "C" void kernel_launch(void* const* d_in, const int* in_sizes, int n_in,
                              void* d_out, int out_size, void* d_ws, size_t ws_size,
                              hipStream_t stream) {
    const float* x     = (const float*)d_in[0];
    const float* gamma = (const float*)d_in[1];
    const float* beta  = (const float*)d_in[2];
    const float* W     = (const float*)d_in[3];
    const float* b     = (const float*)d_in[4];
    float* out = (float*)d_out;

    unsigned char* wsb = (unsigned char*)d_ws;
    float* P    = (float*)wsb;                               // 8*SA f32 = 9,437,184 B
    float* mu   = (float*)(wsb + 9437184);                   // 16 KB
    float* rstd = (float*)(wsb + 9437184 + 16384);           // 16 KB
    unsigned short* Ahi  = (unsigned short*)(wsb + 9469952); // 4 MB
    unsigned short* Alo  = Ahi  + (size_t)S_TOTAL*DDIM;      // 4 MB
    unsigned short* WhiT = Alo  + (size_t)S_TOTAL*DDIM;      // 0.88 MB
    unsigned short* WloT = WhiT + (size_t)NPROJ*DDIM;        // 0.88 MB

    hipMemsetAsync(d_out, 0, (size_t)SA * sizeof(float), stream);

    ln_stats_kernel<<<dim3(S_TOTAL/4), dim3(256), 0, stream>>>(x, mu, rstd);
    prep_kernel<<<dim3(2048 + 432), dim3(256), 0, stream>>>(x, gamma, beta, W, mu, rstd,
                                                            Ahi, Alo, WhiT, WloT);
    gemm_kernel<<<dim3(S_TOTAL/GBM, NPROJ/GBN), dim3(256), 0, stream>>>(Ahi, Alo, WhiT, WloT,
                                                                        b, P, out);
    osc_kernel<<<dim3(S_TOTAL/64, AXES/2), dim3(256), 0, stream>>>(P, out);
}

// Round 4
// 73.671 us; speedup vs baseline: 17.0219x; 1.5464x over previous
//
#include <hip/hip_runtime.h>
#include <math.h>

#define S_TOTAL 4096
#define DDIM    512
#define AXES    72
#define NPROJ   864
#define T_PROP  600
#define SA      (S_TOTAL*AXES)
#define LN_EPS  1e-5f
#define AMP_CUT 4e-6f

typedef __attribute__((ext_vector_type(8))) short short8;
typedef __attribute__((ext_vector_type(4))) float f32x4;

__device__ __forceinline__ float softplus_f(float x) {
    return fmaxf(x, 0.f) + log1pf(expf(-fabsf(x)));
}
__device__ __forceinline__ unsigned short bf_hi(float f) {
    return (unsigned short)(__float_as_uint(f) >> 16);
}

// ---------------- 1. fused LN-stats + bf16 split + W^T split ----------------
__global__ __launch_bounds__(256) void prep_kernel(
        const float* __restrict__ x, const float* __restrict__ gamma,
        const float* __restrict__ beta, const float* __restrict__ W,
        unsigned short* __restrict__ Ahi, unsigned short* __restrict__ Alo,
        unsigned short* __restrict__ WhiT, unsigned short* __restrict__ WloT) {
    __shared__ float Wt[32][33];
    int tid = threadIdx.x;
    int b = blockIdx.x;
    if (b < 1024) {
        // one wave per row: stats + normalize + split, single pass
        int lane = tid & 63, w = tid >> 6;
        int row = b*4 + w;
        const float4* xr = reinterpret_cast<const float4*>(x + (size_t)row * DDIM);
        float4 xv[2] = { xr[lane], xr[lane + 64] };
        float sum = 0.f, ssq = 0.f;
#pragma unroll
        for (int c = 0; c < 2; ++c) {
            sum += (xv[c].x + xv[c].y) + (xv[c].z + xv[c].w);
            ssq += xv[c].x*xv[c].x + xv[c].y*xv[c].y + xv[c].z*xv[c].z + xv[c].w*xv[c].w;
        }
#pragma unroll
        for (int off = 1; off < 64; off <<= 1) {
            sum += __shfl_xor(sum, off);
            ssq += __shfl_xor(ssq, off);
        }
        float m = sum * (1.f/DDIM);
        float r = rsqrtf(ssq * (1.f/DDIM) - m*m + LN_EPS);
        const float4* gp = reinterpret_cast<const float4*>(gamma);
        const float4* bp = reinterpret_cast<const float4*>(beta);
#pragma unroll
        for (int c = 0; c < 2; ++c) {
            float4 gv = gp[lane + 64*c], bv = bp[lane + 64*c];
            float xn[4] = {(xv[c].x-m)*r*gv.x+bv.x, (xv[c].y-m)*r*gv.y+bv.y,
                           (xv[c].z-m)*r*gv.z+bv.z, (xv[c].w-m)*r*gv.w+bv.w};
            ushort4 h4, l4;
            unsigned short* hp = &h4.x;
            unsigned short* lp = &l4.x;
#pragma unroll
            for (int j = 0; j < 4; ++j) {
                unsigned short hi = bf_hi(xn[j]);
                float fhi = __uint_as_float((unsigned)hi << 16);
                hp[j] = hi;
                lp[j] = bf_hi(xn[j] - fhi);
            }
            size_t o = (size_t)row*DDIM + 256*c + lane*4;
            *reinterpret_cast<ushort4*>(&Ahi[o]) = h4;
            *reinterpret_cast<ushort4*>(&Alo[o]) = l4;
        }
    } else {
        // W transpose + split: 32x32 tiles, 16 k-tiles x 27 n-tiles
        int wb = b - 1024;
        int bk = wb / 27, bn = wb - bk*27;
        int tx = tid & 31, ty0 = tid >> 5;
#pragma unroll
        for (int rr = 0; rr < 4; ++rr) {
            int ty = ty0 + rr*8;
            Wt[ty][tx] = W[(size_t)(bk*32 + ty)*NPROJ + bn*32 + tx];
        }
        __syncthreads();
#pragma unroll
        for (int rr = 0; rr < 4; ++rr) {
            int ny = ty0 + rr*8;
            int n = bn*32 + ny;
            int k = bk*32 + tx;
            float f = Wt[tx][ny];
            unsigned short hi = bf_hi(f);
            float fhi = __uint_as_float((unsigned)hi << 16);
            WhiT[(size_t)n*DDIM + k] = hi;
            WloT[(size_t)n*DDIM + k] = bf_hi(f - fhi);
        }
    }
}

// ---------------- 2. split-bf16 MFMA GEMM + param transforms ----------------
#define GBM 64
#define GBN 96
#define GBK 64

__global__ __launch_bounds__(256) void gemm_kernel(
        const unsigned short* __restrict__ Ahi, const unsigned short* __restrict__ Alo,
        const unsigned short* __restrict__ WhiT, const unsigned short* __restrict__ WloT,
        const float* __restrict__ bias,
        float* __restrict__ P, float* __restrict__ out) {
    __shared__ __align__(16) unsigned short Xs[64][72];
    __shared__ __align__(16) unsigned short Ws2[96][72];

    int tid  = threadIdx.x;
    int lane = tid & 63;
    int wv   = tid >> 6;
    int wm   = wv & 1;
    int wn   = wv >> 1;
    int sBase = blockIdx.x * GBM;
    int nBase = blockIdx.y * GBN;

    f32x4 acc[2][3] = {};
    uint4 pfX[2], pfW[3];

    int rowX[2], c16X[2], rowW[3], c16W[3];
#pragma unroll
    for (int j = 0; j < 2; ++j) { int ch = j*256 + tid; rowX[j] = ch >> 3; c16X[j] = ch & 7; }
#pragma unroll
    for (int j = 0; j < 3; ++j) { int ch = j*256 + tid; rowW[j] = ch >> 3; c16W[j] = ch & 7; }

#pragma unroll 1
    for (int kt = 0; kt < 24; ++kt) {
        {
            int seg = kt >> 3;
            int k0  = (kt & 7) * GBK;
            const unsigned short* xs = (seg == 1) ? Alo : Ahi;
            const unsigned short* ws = (seg == 2) ? WloT : WhiT;
#pragma unroll
            for (int j = 0; j < 2; ++j)
                pfX[j] = *reinterpret_cast<const uint4*>(xs + (size_t)(sBase+rowX[j])*DDIM + k0 + c16X[j]*8);
#pragma unroll
            for (int j = 0; j < 3; ++j)
                pfW[j] = *reinterpret_cast<const uint4*>(ws + (size_t)(nBase+rowW[j])*DDIM + k0 + c16W[j]*8);
        }
#pragma unroll
        for (int j = 0; j < 2; ++j)
            *reinterpret_cast<uint4*>(&Xs[rowX[j]][c16X[j]*8]) = pfX[j];
#pragma unroll
        for (int j = 0; j < 3; ++j)
            *reinterpret_cast<uint4*>(&Ws2[rowW[j]][c16W[j]*8]) = pfW[j];
        __syncthreads();

#pragma unroll
        for (int kk = 0; kk < 2; ++kk) {
            int koff = kk*32 + ((lane>>4)<<3);
            short8 xf[2], wf[3];
#pragma unroll
            for (int mi = 0; mi < 2; ++mi)
                xf[mi] = *reinterpret_cast<const short8*>(&Xs[wm*32 + mi*16 + (lane&15)][koff]);
#pragma unroll
            for (int nf = 0; nf < 3; ++nf)
                wf[nf] = *reinterpret_cast<const short8*>(&Ws2[wn*48 + nf*16 + (lane&15)][koff]);
#pragma unroll
            for (int mi = 0; mi < 2; ++mi)
#pragma unroll
                for (int nf = 0; nf < 3; ++nf)
                    acc[mi][nf] = __builtin_amdgcn_mfma_f32_16x16x32_bf16(wf[nf], xf[mi], acc[mi][nf], 0, 0, 0);
        }
        __syncthreads();
    }

    int sCol = sBase + wm*32 + (lane & 15);
    int nRowBase = nBase + wn*48 + ((lane>>4)<<2);
#pragma unroll
    for (int mi = 0; mi < 2; ++mi) {
        int s = sCol + mi*16;
#pragma unroll
        for (int nf = 0; nf < 3; ++nf) {
#pragma unroll
            for (int r = 0; r < 4; ++r) {
                int n = nRowBase + nf*16 + r;
                float val = acc[mi][nf][r] + bias[n];
                float sp  = softplus_f(val);
                float sq  = sqrtf(sp);
                int ip = (n * 3641) >> 18;   // n / 72
                int a  = n - ip * 72;
                float res = val;
                if (ip == 0 || ip == 2) res = sq;
                else if (ip == 1 || ip == 3 || ip == 9 || ip == 11) res = sp;
                float* dst = (ip < 8) ? (P + (size_t)ip * SA)
                                      : (out + (size_t)(ip - 7) * SA);
                dst[(size_t)a * S_TOTAL + s] = res;
            }
        }
    }
}

// ---------------- 3. oscillator: order-2 recurrences + rotation scatter ----------------
template<int STEPS>
__device__ __forceinline__ void osc_chunk(
        float& v1a, float& v1b, float& v2a, float& v2b,
        float p1, float q1, float p2, float q2,
        float& acc0, float& acc1, int lane, int lane4) {
#pragma unroll
    for (int i = 0; i < STEPS/2; ++i) {
        {
            const int dt = 2*i;
            v1b = fmaf(p1, v1a, -(q1*v1b));
            v2b = fmaf(p2, v2a, -(q2*v2b));
            float v = v1b + v2b;
            if (dt == 0) {
                acc0 += v;
            } else {
                int addr = (lane4 + (((64-dt)&63)<<2)) & 255;
                float vr = __int_as_float(__builtin_amdgcn_ds_bpermute(addr, __float_as_int(v)));
                bool nw = lane >= dt;
                acc0 += nw ? vr : 0.f;
                acc1 += nw ? 0.f : vr;
            }
        }
        {
            const int dt = 2*i + 1;
            v1a = fmaf(p1, v1b, -(q1*v1a));
            v2a = fmaf(p2, v2b, -(q2*v2a));
            float v = v1a + v2a;
            int addr = (lane4 + (((64-dt)&63)<<2)) & 255;
            float vr = __int_as_float(__builtin_amdgcn_ds_bpermute(addr, __float_as_int(v)));
            bool nw = lane >= dt;
            acc0 += nw ? vr : 0.f;
            acc1 += nw ? 0.f : vr;
        }
    }
}

__global__ __launch_bounds__(256) void osc_kernel(const float* __restrict__ P,
                                                  float* __restrict__ kin) {
    int tid  = threadIdx.x;
    int lane = tid & 63;
    int wv   = tid >> 6;
    int lane4 = lane << 2;
    int sBase = blockIdx.x * 64;
    int a  = blockIdx.y * 2 + (wv >> 1);
    int t0 = (wv & 1) * 300;
    float t0f = (float)t0;

    size_t base = (size_t)a * S_TOTAL + sBase + lane;
    float om1 = P[0*(size_t)SA + base], d1 = P[1*(size_t)SA + base];
    float om2 = P[2*(size_t)SA + base], d2 = P[3*(size_t)SA + base];
    float c1  = P[4*(size_t)SA + base], c2  = P[5*(size_t)SA + base];
    float ph1 = P[6*(size_t)SA + base], ph2 = P[7*(size_t)SA + base];

    // oscillator 1: v_k = p1 v_{k-1} - q1 v_{k-2}; v_k = e1 dcf1^k sin(th0 + k om1)
    float dcf1 = __expf(-0.5f*d1);
    float e1   = c1 * __expf(-0.5f*d1*t0f);
    float s0, c0, so, co;
    __sincosf(fmaf(t0f, om1, ph1), &s0, &c0);
    __sincosf(om1, &so, &co);
    float inv1 = __expf(0.5f*d1);
    float p1 = 2.f*dcf1*co, q1 = dcf1*dcf1;
    float v1a = e1*inv1*(s0*co - c0*so);                       // v_{-1}
    float cs2 = fmaf(2.f*co, co, -1.f), sn2 = 2.f*so*co;
    float v1b = e1*inv1*inv1*(s0*cs2 - c0*sn2);                // v_{-2}
    float amp1 = fabsf(e1);
    float dq1 = q1*q1; dq1*=dq1; dq1*=dq1; dq1*=dq1; dq1*=dq1; // dcf1^64
    // oscillator 2
    float dcf2 = __expf(-0.5f*d2);
    float e2   = c2 * __expf(-0.5f*d2*t0f);
    __sincosf(fmaf(t0f, om2, ph2), &s0, &c0);
    __sincosf(om2, &so, &co);
    float inv2 = __expf(0.5f*d2);
    float p2 = 2.f*dcf2*co, q2 = dcf2*dcf2;
    float v2a = e2*inv2*(s0*co - c0*so);
    cs2 = fmaf(2.f*co, co, -1.f); sn2 = 2.f*so*co;
    float v2b = e2*inv2*inv2*(s0*cs2 - c0*sn2);
    float amp2 = fabsf(e2);
    float dq2 = q2*q2; dq2*=dq2; dq2*=dq2; dq2*=dq2; dq2*=dq2; // dcf2^64

    float acc0 = 0.f, acc1 = 0.f;
    float* kinA = kin + (size_t)a * S_TOTAL;
    int jBase = sBase + t0;
    int ran = 0;

#pragma unroll 1
    for (int c = 0; c < 5; ++c) {
        if (__all(fmaxf(amp1, amp2) < AMP_CUT)) break;
        if (c < 4) osc_chunk<64>(v1a, v1b, v2a, v2b, p1, q1, p2, q2, acc0, acc1, lane, lane4);
        else       osc_chunk<44>(v1a, v1b, v2a, v2b, p1, q1, p2, q2, acc0, acc1, lane, lane4);
        int j = jBase + lane;
        if (j < S_TOTAL) unsafeAtomicAdd(&kinA[j], acc0);
        acc0 = acc1; acc1 = 0.f;
        jBase += 64;
        amp1 *= dq1; amp2 *= dq2;
        ran = 1;
        if (jBase >= S_TOTAL) { ran = 0; break; }   // everything further is discarded
    }
    if (ran) {
        int j = jBase + lane;
        if (j < S_TOTAL) unsafeAtomicAdd(&kinA[j], acc0);
    }
}

// ---------------- launch ----------------
extern "C" void kernel_launch(void* const* d_in, const int* in_sizes, int n_in,
                              void* d_out, int out_size, void* d_ws, size_t ws_size,
                              hipStream_t stream) {
    const float* x     = (const float*)d_in[0];
    const float* gamma = (const float*)d_in[1];
    const float* beta  = (const float*)d_in[2];
    const float* W     = (const float*)d_in[3];
    const float* b     = (const float*)d_in[4];
    float* out = (float*)d_out;

    unsigned char* wsb = (unsigned char*)d_ws;
    float* P    = (float*)wsb;                               // 8*SA f32 = 9,437,184 B
    unsigned short* Ahi  = (unsigned short*)(wsb + 9437184); // 4 MB
    unsigned short* Alo  = Ahi  + (size_t)S_TOTAL*DDIM;      // 4 MB
    unsigned short* WhiT = Alo  + (size_t)S_TOTAL*DDIM;      // 0.88 MB
    unsigned short* WloT = WhiT + (size_t)NPROJ*DDIM;        // 0.88 MB

    hipMemsetAsync(d_out, 0, (size_t)SA * sizeof(float), stream);

    prep_kernel<<<dim3(1024 + 432), dim3(256), 0, stream>>>(x, gamma, beta, W,
                                                            Ahi, Alo, WhiT, WloT);
    gemm_kernel<<<dim3(S_TOTAL/GBM, NPROJ/GBN), dim3(256), 0, stream>>>(Ahi, Alo, WhiT, WloT,
                                                                        b, P, out);
    osc_kernel<<<dim3(S_TOTAL/64, AXES/2), dim3(256), 0, stream>>>(P, out);
}